// Round 8
// baseline (422.078 us; speedup 1.0000x reference)
//
#include <hip/hip_runtime.h>
#include <hip/hip_fp16.h>
#include <math.h>

// Problem dims
#define NN   8192
#define KD   8192
#define HID  200
#define NP   224    // HID padded to 14*16
#define OUTC 5

// GEMM tiling
#define BM   64
#define BK   32
#define KS   8
#define KCH  (KD / KS)     // 1024
#define NT   (KCH / BK)    // 32 K-steps per block
#define TUB  1024          // B tile 16B-units (256 rows x 4; rows 224..255 padding, never read)
// LDS swizzle (4-unit rows): logical (r, c) -> phys unit (r*4 + (c ^ (r&3))) ^ (r&4)
// bijective; 16 consecutive rows at fixed c span all unit%8 slots -> conflict-free b128 reads.

typedef _Float16 f16;
typedef __attribute__((ext_vector_type(4))) _Float16 f16x4;
typedef __attribute__((ext_vector_type(8))) _Float16 f16x8;
typedef __attribute__((ext_vector_type(4))) float f32x4;

__device__ __forceinline__ int swzu(int r, int c) {
    return (r * 4 + (c ^ (r & 3))) ^ (r & 4);
}

__device__ __forceinline__ void fill16(const f16* g, f16* l) {
    __builtin_amdgcn_global_load_lds(
        (const __attribute__((address_space(1))) void*)g,
        (__attribute__((address_space(3))) void*)l, 16, 0, 0);
}

// ============ 1. W1 [8192][200] fp32 -> BW1 swizzled-tile fp16 (2 tiles of 32k per block) ======
__global__ __launch_bounds__(256) void k_prep_w1(const float* __restrict__ W1,
                                                 f16* __restrict__ Bsw) {
    __shared__ float tile[64][65];
    const int bx = blockIdx.x;          // 0..127 : k0 = bx*64 (tiles 2bx, 2bx+1)
    const int n0 = blockIdx.y * 64;
    const int k0 = bx * 64;
    const int t = threadIdx.x;
    #pragma unroll
    for (int q = 0; q < 4; ++q) {
        int idx4 = t + q * 256;
        int kk = idx4 >> 4, nn4 = (idx4 & 15) * 4;
        int n = n0 + nn4;
        float4 v = {0.f, 0.f, 0.f, 0.f};
        if (n + 4 <= HID) v = *(const float4*)(W1 + (size_t)(k0 + kk) * HID + n);
        tile[kk][nn4 + 0] = v.x; tile[kk][nn4 + 1] = v.y;
        tile[kk][nn4 + 2] = v.z; tile[kk][nn4 + 3] = v.w;
    }
    __syncthreads();
    #pragma unroll
    for (int p2 = 0; p2 < 2; ++p2) {
        int u = t + p2 * 256;               // 0..511
        int rl = u >> 3, cc = u & 7;
        int ktl = cc >> 2, c = cc & 3;
        int r = n0 + rl;
        if (r < NP) {
            f16x8 o;
            #pragma unroll
            for (int h = 0; h < 8; ++h) o[h] = (f16)tile[ktl * 32 + c * 8 + h][rl];
            *(f16x8*)(Bsw + ((size_t)(bx * 2 + ktl) * TUB + swzu(r, c)) * 8) = o;
        }
    }
}

// ============ 2. GEMM: CP[ky][row][c] (f16) = A[:, kchunk] @ B ============
// A loaded DIRECTLY global->registers (no LDS round trip); B via global_load_lds dbuf.
// 256 thr (4 waves 2m x 2n), 4 blocks/CU. One barrier per K-step; counted vmcnt.
__global__ __launch_bounds__(256, 4) void k_gemm(const float* __restrict__ A,
                                                 const f16* __restrict__ Bsw,
                                                 f16* __restrict__ CP) {
    __shared__ __align__(16) f16 Bf0[TUB * 8], Bf1[TUB * 8];   // 2 x 16 KB

    const int t = threadIdx.x;
    const int lane = t & 63, wv = t >> 6;
    const int wm = wv >> 1, wn = wv & 1;
    const int l15 = lane & 15, g = lane >> 4;
    const int bid = blockIdx.x;
    const int ky = bid & 7;            // k-chunk; round-robin -> per-XCD B slice in L2
    const int bx = bid >> 3;
    const int m0 = bx * BM;
    const int kt0 = ky * NT;
    const size_t kc0 = (size_t)ky * KCH;

    // A fragment addresses: row = m0 + wm*32 + m*16 + l15, k = kc0 + i*BK + g*8
    const float* ap0 = A + (size_t)(m0 + wm * 32 + l15) * KD + kc0 + (size_t)g * 8;
    const float* ap1 = ap0 + (size_t)16 * KD;
    const f16* bsrc = Bsw + ((size_t)kt0 * TUB + (size_t)t) * 8;

    // B read offsets (halves), hoisted
    int bofs[7];
    #pragma unroll
    for (int n = 0; n < 7; ++n) bofs[n] = swzu(wn * 112 + n * 16 + l15, g) * 8;

    f32x4 acc[2][7];
    #pragma unroll
    for (int m = 0; m < 2; ++m)
        #pragma unroll
        for (int n = 0; n < 7; ++n) acc[m][n] = (f32x4){0.f, 0.f, 0.f, 0.f};

    float4 va0, va1, va2, va3, vb0, vb1, vb2, vb3;
#define LOADA(i, V0, V1, V2, V3) { size_t o_ = (size_t)(i) * BK;            \
        V0 = *(const float4*)(ap0 + o_); V1 = *(const float4*)(ap0 + o_ + 4); \
        V2 = *(const float4*)(ap1 + o_); V3 = *(const float4*)(ap1 + o_ + 4); }
#define FILLB(i, BF) { const f16* bs_ = bsrc + (size_t)(i) * (TUB * 8);  \
        fill16(bs_,            &BF[(t      ) * 8]);                      \
        fill16(bs_ + 256 * 8,  &BF[(t + 256) * 8]);                      \
        fill16(bs_ + 512 * 8,  &BF[(t + 512) * 8]);                      \
        fill16(bs_ + 768 * 8,  &BF[(t + 768) * 8]); }
#define CVT(F0, F1, V0, V1, V2, V3) {                                       \
        F0[0]=(f16)V0.x; F0[1]=(f16)V0.y; F0[2]=(f16)V0.z; F0[3]=(f16)V0.w;  \
        F0[4]=(f16)V1.x; F0[5]=(f16)V1.y; F0[6]=(f16)V1.z; F0[7]=(f16)V1.w;  \
        F1[0]=(f16)V2.x; F1[1]=(f16)V2.y; F1[2]=(f16)V2.z; F1[3]=(f16)V2.w;  \
        F1[4]=(f16)V3.x; F1[5]=(f16)V3.y; F1[6]=(f16)V3.z; F1[7]=(f16)V3.w; }
#define MFMA_PH(BF, F0, F1) {                                               \
        _Pragma("unroll")                                                   \
        for (int n = 0; n < 7; ++n) {                                       \
            f16x8 b_ = *(const f16x8*)&BF[bofs[n]];                         \
            acc[0][n] = __builtin_amdgcn_mfma_f32_16x16x32_f16(F0, b_, acc[0][n], 0, 0, 0); \
            acc[1][n] = __builtin_amdgcn_mfma_f32_16x16x32_f16(F1, b_, acc[1][n], 0, 0, 0); } }

    // prologue: B(0) fills + A(0), A(1) register loads in flight
    FILLB(0, Bf0);
    __builtin_amdgcn_sched_barrier(0);
    LOADA(0, va0, va1, va2, va3);
    LOADA(1, vb0, vb1, vb2, vb3);
    __builtin_amdgcn_sched_barrier(0);
    asm volatile("s_waitcnt vmcnt(8)\n\ts_barrier" ::: "memory");   // B(0) ready

    for (int ip = 0; ip < NT / 2; ++ip) {
        const int i = 2 * ip;
        const int iL2 = (i + 2 < NT) ? i + 2 : NT - 1;   // clamped (keeps vmcnt constant)
        const int iF2 = iL2;
        const int iL3 = (i + 3 < NT) ? i + 3 : NT - 1;
        // ---- body A: compute step i from Bf0 ----
        f16x8 fa0, fa1;
        CVT(fa0, fa1, va0, va1, va2, va3);               // compiler waits A(i) loads
        FILLB(i + 1, Bf1);                               // B(i+1) -> other buffer
        __builtin_amdgcn_sched_barrier(0);
        LOADA(iL2, va0, va1, va2, va3);                  // A(i+2) regs in flight (depth 2)
        __builtin_amdgcn_sched_barrier(0);
        __builtin_amdgcn_s_setprio(1);
        MFMA_PH(Bf0, fa0, fa1);
        __builtin_amdgcn_s_setprio(0);
        asm volatile("s_waitcnt vmcnt(4) lgkmcnt(0)\n\ts_barrier" ::: "memory");
        // ---- body B: compute step i+1 from Bf1 ----
        f16x8 fb0, fb1;
        CVT(fb0, fb1, vb0, vb1, vb2, vb3);
        FILLB(iF2, Bf0);
        __builtin_amdgcn_sched_barrier(0);
        LOADA(iL3, vb0, vb1, vb2, vb3);
        __builtin_amdgcn_sched_barrier(0);
        __builtin_amdgcn_s_setprio(1);
        MFMA_PH(Bf1, fb0, fb1);
        __builtin_amdgcn_s_setprio(0);
        asm volatile("s_waitcnt vmcnt(4) lgkmcnt(0)\n\ts_barrier" ::: "memory");
    }
#undef LOADA
#undef FILLB
#undef CVT
#undef MFMA_PH

    f16* o = CP + (size_t)ky * ((size_t)NN * NP);
    #pragma unroll
    for (int m = 0; m < 2; ++m) {
        #pragma unroll
        for (int n = 0; n < 7; ++n) {
            int rb = m0 + wm * 32 + m * 16 + g * 4;
            int c = wn * 112 + n * 16 + l15;
            #pragma unroll
            for (int r = 0; r < 4; ++r)
                o[(size_t)(rb + r) * NP + c] = (f16)acc[m][n][r];
        }
    }
}

// ============ 3. combine partials -> BS1 (swizzled-tile, transposed) ============
__global__ __launch_bounds__(256) void k_combine_b(const f16* __restrict__ CP,
                                                   f16* __restrict__ Bsw) {
    __shared__ float tile[64][65];
    const size_t SZ = (size_t)NN * NP;
    const int bx = blockIdx.x;          // k0 = bx*64 (S1 rows) -> tiles 2bx, 2bx+1
    const int n0 = blockIdx.y * 64;
    const int k0 = bx * 64;
    const int t = threadIdx.x;
    #pragma unroll
    for (int q = 0; q < 4; ++q) {
        int idx4 = t + q * 256;
        int kk = idx4 >> 4, nn4 = (idx4 & 15) * 4;
        int n = n0 + nn4;
        float s0 = 0.f, s1 = 0.f, s2 = 0.f, s3 = 0.f;
        if (n < NP) {
            #pragma unroll
            for (int p = 0; p < KS; ++p) {
                f16x4 v = *(const f16x4*)(CP + (size_t)p * SZ + (size_t)(k0 + kk) * NP + n);
                s0 += (float)v[0]; s1 += (float)v[1]; s2 += (float)v[2]; s3 += (float)v[3];
            }
        }
        tile[kk][nn4 + 0] = s0; tile[kk][nn4 + 1] = s1;
        tile[kk][nn4 + 2] = s2; tile[kk][nn4 + 3] = s3;
    }
    __syncthreads();
    #pragma unroll
    for (int p2 = 0; p2 < 2; ++p2) {
        int u = t + p2 * 256;
        int rl = u >> 3, cc = u & 7;
        int ktl = cc >> 2, c = cc & 3;
        int r = n0 + rl;
        if (r < NP) {
            f16x8 o;
            #pragma unroll
            for (int h = 0; h < 8; ++h) o[h] = (f16)tile[ktl * 32 + c * 8 + h][rl];
            *(f16x8*)(Bsw + ((size_t)(bx * 2 + ktl) * TUB + swzu(r, c)) * 8) = o;
        }
    }
}

// ============ 4. fused tail: H = relu(sum CP + b1); S2T = (H @ W2)^T ============
__global__ __launch_bounds__(256) void k_tail(const f16* __restrict__ CP,
                                              const float* __restrict__ b1,
                                              const float* __restrict__ W2,
                                              float* __restrict__ S2T) {
    const int tx = threadIdx.x;         // 0..31
    const int ty = threadIdx.y;         // 0..7
    const int row = blockIdx.x * 8 + ty;
    float s[OUTC] = {0.f, 0.f, 0.f, 0.f, 0.f};
    if (tx < 28) {
        const size_t SZ = (size_t)NN * NP;
        const size_t off = (size_t)row * NP + tx * 8;
        float h[8] = {0.f,0.f,0.f,0.f,0.f,0.f,0.f,0.f};
        #pragma unroll
        for (int p = 0; p < KS; ++p) {
            f16x8 v = *(const f16x8*)(CP + (size_t)p * SZ + off);
            #pragma unroll
            for (int j = 0; j < 8; ++j) h[j] += (float)v[j];
        }
        #pragma unroll
        for (int j = 0; j < 8; ++j) {
            int c = tx * 8 + j;
            if (c < HID) {
                float hv = fmaxf(h[j] + b1[c], 0.f);
                #pragma unroll
                for (int q = 0; q < OUTC; ++q) s[q] += hv * W2[c * OUTC + q];
            }
        }
    }
    #pragma unroll
    for (int q = 0; q < OUTC; ++q)
        #pragma unroll
        for (int off2 = 16; off2; off2 >>= 1) s[q] += __shfl_down(s[q], off2, 32);
    if (tx == 0) {
        #pragma unroll
        for (int q = 0; q < OUTC; ++q) S2T[(size_t)q * NN + row] = s[q];
    }
}

// ============ 5. softmax(adj @ S2 + b2) -> out (adj fp32) ============
__global__ __launch_bounds__(256) void k_final(const float* __restrict__ adj,
                                               const float* __restrict__ S2T,
                                               const float* __restrict__ b2,
                                               float* __restrict__ out) {
    __shared__ float red[4][8][OUTC];
    const int t = threadIdx.x, wave = t >> 6, lane = t & 63;
    const int row0 = blockIdx.x * 8;
    float acc[8][OUTC];
    #pragma unroll
    for (int r = 0; r < 8; ++r)
        #pragma unroll
        for (int c = 0; c < OUTC; ++c) acc[r][c] = 0.f;

    for (int jj = 0; jj < 8; ++jj) {
        int kb = (t + jj * 256) * 4;
        float4 s2[OUTC];
        #pragma unroll
        for (int c = 0; c < OUTC; ++c) s2[c] = *(const float4*)(S2T + (size_t)c * NN + kb);
        #pragma unroll
        for (int r = 0; r < 8; ++r) {
            float4 a = *(const float4*)(adj + (size_t)(row0 + r) * KD + kb);
            #pragma unroll
            for (int c = 0; c < OUTC; ++c)
                acc[r][c] += a.x * s2[c].x + a.y * s2[c].y + a.z * s2[c].z + a.w * s2[c].w;
        }
    }
    #pragma unroll
    for (int r = 0; r < 8; ++r)
        #pragma unroll
        for (int c = 0; c < OUTC; ++c) {
            float v = acc[r][c];
            #pragma unroll
            for (int off = 32; off; off >>= 1) v += __shfl_down(v, off, 64);
            if (lane == 0) red[wave][r][c] = v;
        }
    __syncthreads();
    if (t < 8) {
        int r = t;
        float lg[OUTC];
        #pragma unroll
        for (int c = 0; c < OUTC; ++c)
            lg[c] = red[0][r][c] + red[1][r][c] + red[2][r][c] + red[3][r][c] + b2[c];
        float mx = lg[0];
        #pragma unroll
        for (int c = 1; c < OUTC; ++c) mx = fmaxf(mx, lg[c]);
        float e[OUTC], ssum = 0.f;
        #pragma unroll
        for (int c = 0; c < OUTC; ++c) { e[c] = expf(lg[c] - mx); ssum += e[c]; }
        float inv = 1.0f / ssum;
        #pragma unroll
        for (int c = 0; c < OUTC; ++c) out[(size_t)(row0 + r) * OUTC + c] = e[c] * inv;
    }
}

// ===================== launcher =====================
extern "C" void kernel_launch(void* const* d_in, const int* in_sizes, int n_in,
                              void* d_out, int out_size, void* d_ws, size_t ws_size,
                              hipStream_t stream) {
    const float* x   = (const float*)d_in[0];
    const float* adj = (const float*)d_in[1];
    const float* W1  = (const float*)d_in[2];
    const float* b1  = (const float*)d_in[3];
    const float* W2  = (const float*)d_in[4];
    const float* b2  = (const float*)d_in[5];
    float* out = (float*)d_out;

    char* ws = (char*)d_ws;
    const size_t BSZ = (size_t)256 * TUB * 16;                 // 4 MB per B' array
    f16*   BW1 = (f16*)(ws);
    f16*   BS1 = (f16*)(ws + BSZ);
    float* S2T = (float*)(ws + 2 * BSZ);
    f16*   CP  = (f16*)(ws + 2 * BSZ + 256 * 1024);            // 8 * NN*NP f16 = 29.4 MB

    // 1. W1 -> swizzled-tile fp16 (B' format)
    k_prep_w1<<<dim3(128, 4), 256, 0, stream>>>(W1, BW1);
    // 2. S1 = x @ W1 (K-split fp16 partials)
    k_gemm<<<dim3(1024), 256, 0, stream>>>(x, BW1, CP);
    // 3. reduce partials -> BS1 (B' format, transposed)
    k_combine_b<<<dim3(128, 4), 256, 0, stream>>>(CP, BS1);
    // 4. adj @ S1 (K-split fp16 partials)
    k_gemm<<<dim3(1024), 256, 0, stream>>>(adj, BS1, CP);
    // 5. fused: H = relu(sum + b1); S2^T = (H @ W2)^T
    k_tail<<<dim3(NN / 8), dim3(32, 8), 0, stream>>>(CP, b1, W2, S2T);
    // 6. softmax(adj @ S2 + b2)
    k_final<<<dim3(NN / 8), 256, 0, stream>>>(adj, S2T, b2, out);
}

// Round 9
// 337.256 us; speedup vs baseline: 1.2515x; 1.2515x over previous
//
#include <hip/hip_runtime.h>
#include <hip/hip_fp16.h>
#include <math.h>

// Problem dims
#define NN   8192
#define KD   8192
#define HID  200
#define NP   224    // HID padded to 14*16
#define OUTC 5

// GEMM tiling
#define BM   64
#define BK   32
#define KS   8
#define KCH  (KD / KS)     // 1024
#define NT   (KCH / BK)    // 32 K-steps per block
#define TUB  896           // B tile 16B-units (224 rows x 4), PLAIN layout: unit = r*4 + g

typedef _Float16 f16;
typedef __attribute__((ext_vector_type(4))) _Float16 f16x4;
typedef __attribute__((ext_vector_type(8))) _Float16 f16x8;
typedef __attribute__((ext_vector_type(4))) float f32x4;

// ============ 1. W1 [8192][200] fp32 -> BW1 plain-tile fp16 ============
// tile kt (32 k) x 224 cols; unit (r=col, g=k-group) at r*4+g; halves = k g*8..g*8+7.
__global__ __launch_bounds__(256) void k_prep_w1(const float* __restrict__ W1,
                                                 f16* __restrict__ Bt) {
    __shared__ float tile[64][65];
    const int bx = blockIdx.x;          // 0..127 : k0 = bx*64 (tiles 2bx, 2bx+1)
    const int n0 = blockIdx.y * 64;
    const int k0 = bx * 64;
    const int t = threadIdx.x;
    #pragma unroll
    for (int q = 0; q < 4; ++q) {
        int idx4 = t + q * 256;
        int kk = idx4 >> 4, nn4 = (idx4 & 15) * 4;
        int n = n0 + nn4;
        float4 v = {0.f, 0.f, 0.f, 0.f};
        if (n + 4 <= HID) v = *(const float4*)(W1 + (size_t)(k0 + kk) * HID + n);
        tile[kk][nn4 + 0] = v.x; tile[kk][nn4 + 1] = v.y;
        tile[kk][nn4 + 2] = v.z; tile[kk][nn4 + 3] = v.w;
    }
    __syncthreads();
    #pragma unroll
    for (int p2 = 0; p2 < 2; ++p2) {
        int u = t + p2 * 256;               // 0..511
        int rl = u >> 3, cc = u & 7;
        int ktl = cc >> 2, c = cc & 3;
        int r = n0 + rl;
        if (r < NP) {
            f16x8 o;
            #pragma unroll
            for (int h = 0; h < 8; ++h) o[h] = (f16)tile[ktl * 32 + c * 8 + h][rl];
            *(f16x8*)(Bt + ((size_t)(bx * 2 + ktl) * TUB + (size_t)r * 4 + c) * 8) = o;
        }
    }
}

// ============ 2. GEMM: CP[ky][row][c] (f16) = A[:, kchunk] @ B ============
// NO LDS, NO barriers. 256 thr (4 waves 2m x 2n). A global->reg (depth-2 prefetch);
// B frags direct from plain-tile buffer (L1/L2-hot). Waves fully independent -> TLP hides latency.
__global__ __launch_bounds__(256, 2) void k_gemm(const float* __restrict__ A,
                                                 const f16* __restrict__ Bt,
                                                 f16* __restrict__ CP) {
    const int t = threadIdx.x;
    const int lane = t & 63, wv = t >> 6;
    const int wm = wv >> 1, wn = wv & 1;
    const int l15 = lane & 15, g = lane >> 4;
    const int bid = blockIdx.x;
    const int ky = bid & 7;            // k-chunk; round-robin -> per-XCD B slice in L2
    const int bx = bid >> 3;
    const int m0 = bx * BM;
    const int kt0 = ky * NT;
    const size_t kc0 = (size_t)ky * KCH;

    // A fragment addresses: row = m0 + wm*32 + m*16 + l15, k = kc0 + i*BK + g*8
    const float* ap0 = A + (size_t)(m0 + wm * 32 + l15) * KD + kc0 + (size_t)g * 8;
    const float* ap1 = ap0 + (size_t)16 * KD;
    // B frag base: lane (l15,g) of n-frag n in tile kt -> unit (wn*112 + n*16 + l15)*4 + g
    const f16* bp = Bt + ((size_t)kt0 * TUB + (size_t)((wn * 112 + l15) * 4 + g)) * 8;

    f32x4 acc[2][7];
    #pragma unroll
    for (int m = 0; m < 2; ++m)
        #pragma unroll
        for (int n = 0; n < 7; ++n) acc[m][n] = (f32x4){0.f, 0.f, 0.f, 0.f};

    float4 va0, va1, va2, va3, vb0, vb1, vb2, vb3;
#define LOADA(i, V0, V1, V2, V3) { size_t o_ = (size_t)(i) * BK;              \
        V0 = *(const float4*)(ap0 + o_); V1 = *(const float4*)(ap0 + o_ + 4);  \
        V2 = *(const float4*)(ap1 + o_); V3 = *(const float4*)(ap1 + o_ + 4); }

    // body: B(i) loads -> A(i+1) loads -> fence -> cvt A(i) -> 14 MFMA
#define BODY(i, HN, C0, C1, C2, C3, N0, N1, N2, N3) {                          \
        const f16* bpt_ = bp + (size_t)(i) * (TUB * 8);                        \
        f16x8 bb[7];                                                           \
        _Pragma("unroll")                                                      \
        for (int n = 0; n < 7; ++n) bb[n] = *(const f16x8*)(bpt_ + n * 512);   \
        if (HN) LOADA((i) + 1, N0, N1, N2, N3);                                \
        __builtin_amdgcn_sched_barrier(0);                                     \
        f16x8 fa0_, fa1_;                                                      \
        fa0_[0]=(f16)C0.x; fa0_[1]=(f16)C0.y; fa0_[2]=(f16)C0.z; fa0_[3]=(f16)C0.w; \
        fa0_[4]=(f16)C1.x; fa0_[5]=(f16)C1.y; fa0_[6]=(f16)C1.z; fa0_[7]=(f16)C1.w; \
        fa1_[0]=(f16)C2.x; fa1_[1]=(f16)C2.y; fa1_[2]=(f16)C2.z; fa1_[3]=(f16)C2.w; \
        fa1_[4]=(f16)C3.x; fa1_[5]=(f16)C3.y; fa1_[6]=(f16)C3.z; fa1_[7]=(f16)C3.w; \
        __builtin_amdgcn_s_setprio(1);                                         \
        _Pragma("unroll")                                                      \
        for (int n = 0; n < 7; ++n) {                                          \
            acc[0][n] = __builtin_amdgcn_mfma_f32_16x16x32_f16(fa0_, bb[n], acc[0][n], 0, 0, 0); \
            acc[1][n] = __builtin_amdgcn_mfma_f32_16x16x32_f16(fa1_, bb[n], acc[1][n], 0, 0, 0); } \
        __builtin_amdgcn_s_setprio(0); }

    LOADA(0, va0, va1, va2, va3);
    #pragma unroll 1
    for (int ip = 0; ip < NT / 2; ++ip) {
        const int i = 2 * ip;
        BODY(i,     true,        va0, va1, va2, va3, vb0, vb1, vb2, vb3);
        BODY(i + 1, i + 2 < NT,  vb0, vb1, vb2, vb3, va0, va1, va2, va3);
    }
#undef LOADA
#undef BODY

    f16* o = CP + (size_t)ky * ((size_t)NN * NP);
    #pragma unroll
    for (int m = 0; m < 2; ++m) {
        #pragma unroll
        for (int n = 0; n < 7; ++n) {
            int rb = m0 + wm * 32 + m * 16 + g * 4;
            int c = wn * 112 + n * 16 + l15;
            #pragma unroll
            for (int r = 0; r < 4; ++r)
                o[(size_t)(rb + r) * NP + c] = (f16)acc[m][n][r];
        }
    }
}

// ============ 3. combine partials -> BS1 (plain-tile, transposed) ============
__global__ __launch_bounds__(256) void k_combine_b(const f16* __restrict__ CP,
                                                   f16* __restrict__ Bt) {
    __shared__ float tile[64][65];
    const size_t SZ = (size_t)NN * NP;
    const int bx = blockIdx.x;          // k0 = bx*64 (S1 rows) -> tiles 2bx, 2bx+1
    const int n0 = blockIdx.y * 64;
    const int k0 = bx * 64;
    const int t = threadIdx.x;
    #pragma unroll
    for (int q = 0; q < 4; ++q) {
        int idx4 = t + q * 256;
        int kk = idx4 >> 4, nn4 = (idx4 & 15) * 4;
        int n = n0 + nn4;
        float s0 = 0.f, s1 = 0.f, s2 = 0.f, s3 = 0.f;
        if (n < NP) {
            #pragma unroll
            for (int p = 0; p < KS; ++p) {
                f16x4 v = *(const f16x4*)(CP + (size_t)p * SZ + (size_t)(k0 + kk) * NP + n);
                s0 += (float)v[0]; s1 += (float)v[1]; s2 += (float)v[2]; s3 += (float)v[3];
            }
        }
        tile[kk][nn4 + 0] = s0; tile[kk][nn4 + 1] = s1;
        tile[kk][nn4 + 2] = s2; tile[kk][nn4 + 3] = s3;
    }
    __syncthreads();
    #pragma unroll
    for (int p2 = 0; p2 < 2; ++p2) {
        int u = t + p2 * 256;
        int rl = u >> 3, cc = u & 7;
        int ktl = cc >> 2, c = cc & 3;
        int r = n0 + rl;
        if (r < NP) {
            f16x8 o;
            #pragma unroll
            for (int h = 0; h < 8; ++h) o[h] = (f16)tile[ktl * 32 + c * 8 + h][rl];
            *(f16x8*)(Bt + ((size_t)(bx * 2 + ktl) * TUB + (size_t)r * 4 + c) * 8) = o;
        }
    }
}

// ============ 4. fused tail: H = relu(sum CP + b1); S2T = (H @ W2)^T ============
__global__ __launch_bounds__(256) void k_tail(const f16* __restrict__ CP,
                                              const float* __restrict__ b1,
                                              const float* __restrict__ W2,
                                              float* __restrict__ S2T) {
    const int tx = threadIdx.x;         // 0..31
    const int ty = threadIdx.y;         // 0..7
    const int row = blockIdx.x * 8 + ty;
    float s[OUTC] = {0.f, 0.f, 0.f, 0.f, 0.f};
    if (tx < 28) {
        const size_t SZ = (size_t)NN * NP;
        const size_t off = (size_t)row * NP + tx * 8;
        float h[8] = {0.f,0.f,0.f,0.f,0.f,0.f,0.f,0.f};
        #pragma unroll
        for (int p = 0; p < KS; ++p) {
            f16x8 v = *(const f16x8*)(CP + (size_t)p * SZ + off);
            #pragma unroll
            for (int j = 0; j < 8; ++j) h[j] += (float)v[j];
        }
        #pragma unroll
        for (int j = 0; j < 8; ++j) {
            int c = tx * 8 + j;
            if (c < HID) {
                float hv = fmaxf(h[j] + b1[c], 0.f);
                #pragma unroll
                for (int q = 0; q < OUTC; ++q) s[q] += hv * W2[c * OUTC + q];
            }
        }
    }
    #pragma unroll
    for (int q = 0; q < OUTC; ++q)
        #pragma unroll
        for (int off2 = 16; off2; off2 >>= 1) s[q] += __shfl_down(s[q], off2, 32);
    if (tx == 0) {
        #pragma unroll
        for (int q = 0; q < OUTC; ++q) S2T[(size_t)q * NN + row] = s[q];
    }
}

// ============ 5. softmax(adj @ S2 + b2) -> out (adj fp32) ============
__global__ __launch_bounds__(256) void k_final(const float* __restrict__ adj,
                                               const float* __restrict__ S2T,
                                               const float* __restrict__ b2,
                                               float* __restrict__ out) {
    __shared__ float red[4][8][OUTC];
    const int t = threadIdx.x, wave = t >> 6, lane = t & 63;
    const int row0 = blockIdx.x * 8;
    float acc[8][OUTC];
    #pragma unroll
    for (int r = 0; r < 8; ++r)
        #pragma unroll
        for (int c = 0; c < OUTC; ++c) acc[r][c] = 0.f;

    for (int jj = 0; jj < 8; ++jj) {
        int kb = (t + jj * 256) * 4;
        float4 s2[OUTC];
        #pragma unroll
        for (int c = 0; c < OUTC; ++c) s2[c] = *(const float4*)(S2T + (size_t)c * NN + kb);
        #pragma unroll
        for (int r = 0; r < 8; ++r) {
            float4 a = *(const float4*)(adj + (size_t)(row0 + r) * KD + kb);
            #pragma unroll
            for (int c = 0; c < OUTC; ++c)
                acc[r][c] += a.x * s2[c].x + a.y * s2[c].y + a.z * s2[c].z + a.w * s2[c].w;
        }
    }
    #pragma unroll
    for (int r = 0; r < 8; ++r)
        #pragma unroll
        for (int c = 0; c < OUTC; ++c) {
            float v = acc[r][c];
            #pragma unroll
            for (int off = 32; off; off >>= 1) v += __shfl_down(v, off, 64);
            if (lane == 0) red[wave][r][c] = v;
        }
    __syncthreads();
    if (t < 8) {
        int r = t;
        float lg[OUTC];
        #pragma unroll
        for (int c = 0; c < OUTC; ++c)
            lg[c] = red[0][r][c] + red[1][r][c] + red[2][r][c] + red[3][r][c] + b2[c];
        float mx = lg[0];
        #pragma unroll
        for (int c = 1; c < OUTC; ++c) mx = fmaxf(mx, lg[c]);
        float e[OUTC], ssum = 0.f;
        #pragma unroll
        for (int c = 0; c < OUTC; ++c) { e[c] = expf(lg[c] - mx); ssum += e[c]; }
        float inv = 1.0f / ssum;
        #pragma unroll
        for (int c = 0; c < OUTC; ++c) out[(size_t)(row0 + r) * OUTC + c] = e[c] * inv;
    }
}

// ===================== launcher =====================
extern "C" void kernel_launch(void* const* d_in, const int* in_sizes, int n_in,
                              void* d_out, int out_size, void* d_ws, size_t ws_size,
                              hipStream_t stream) {
    const float* x   = (const float*)d_in[0];
    const float* adj = (const float*)d_in[1];
    const float* W1  = (const float*)d_in[2];
    const float* b1  = (const float*)d_in[3];
    const float* W2  = (const float*)d_in[4];
    const float* b2  = (const float*)d_in[5];
    float* out = (float*)d_out;

    char* ws = (char*)d_ws;
    const size_t BSZ = (size_t)256 * TUB * 16;                 // 3.67 MB per B' array
    f16*   BW1 = (f16*)(ws);
    f16*   BS1 = (f16*)(ws + BSZ);
    float* S2T = (float*)(ws + 2 * BSZ);
    f16*   CP  = (f16*)(ws + 2 * BSZ + 256 * 1024);            // 8 * NN*NP f16 = 29.4 MB

    // 1. W1 -> plain-tile fp16 (B' format)
    k_prep_w1<<<dim3(128, 4), 256, 0, stream>>>(W1, BW1);
    // 2. S1 = x @ W1 (K-split fp16 partials)
    k_gemm<<<dim3(1024), 256, 0, stream>>>(x, BW1, CP);
    // 3. reduce partials -> BS1 (B' format, transposed)
    k_combine_b<<<dim3(128, 4), 256, 0, stream>>>(CP, BS1);
    // 4. adj @ S1 (K-split fp16 partials)
    k_gemm<<<dim3(1024), 256, 0, stream>>>(adj, BS1, CP);
    // 5. fused: H = relu(sum + b1); S2^T = (H @ W2)^T
    k_tail<<<dim3(NN / 8), dim3(32, 8), 0, stream>>>(CP, b1, W2, S2T);
    // 6. softmax(adj @ S2 + b2)
    k_final<<<dim3(NN / 8), 256, 0, stream>>>(adj, S2T, b2, out);
}

// Round 10
// 285.107 us; speedup vs baseline: 1.4804x; 1.1829x over previous
//
#include <hip/hip_runtime.h>
#include <hip/hip_fp16.h>
#include <math.h>

// Problem dims
#define NN   8192
#define KD   8192
#define HID  200
#define NP   224    // HID padded to 14*16
#define OUTC 5

// GEMM tiling
#define BM   128
#define BK   64
#define KS   8
#define KCH  (KD / KS)     // 1024
#define NT   (KCH / BK)    // 16 K-steps per block
#define TUB  2048          // B tile 16B-units (256 rows x 8; rows 224..255 pad, never consumed)
#define BFSZ (TUB * 8)     // halves per B LDS buffer (32 KB)
// LDS swizzle: logical unit (r, c) -> phys unit r*8 + (c ^ (r&7)); 16B units, 8 per 128B row.
// 16 lanes reading consecutive rows at fixed c span all 8 unit%8 slots -> 2-way banks (free).

typedef _Float16 f16;
typedef __attribute__((ext_vector_type(4))) _Float16 f16x4;
typedef __attribute__((ext_vector_type(8))) _Float16 f16x8;
typedef __attribute__((ext_vector_type(4))) float f32x4;

__device__ __forceinline__ void fill16(const f16* g, f16* l) {
    __builtin_amdgcn_global_load_lds(
        (const __attribute__((address_space(1))) void*)g,
        (__attribute__((address_space(3))) void*)l, 16, 0, 0);
}

// ============ 1. W1 [8192][200] fp32 -> BW1 swizzled-tile fp16 (2 tiles of 64k per block) ======
__global__ __launch_bounds__(256) void k_prep_w1(const float* __restrict__ W1,
                                                 f16* __restrict__ Bsw) {
    __shared__ float tile[64][65];
    const int kt = blockIdx.x;          // 0..127 : k0 = kt*64 -> tile kt (64 k wide)
    const int n0 = blockIdx.y * 64;
    const int k0 = kt * 64;
    const int t = threadIdx.x;
    #pragma unroll
    for (int q = 0; q < 4; ++q) {
        int idx4 = t + q * 256;
        int kk = idx4 >> 4, nn4 = (idx4 & 15) * 4;
        int n = n0 + nn4;
        float4 v = {0.f, 0.f, 0.f, 0.f};
        if (n + 4 <= HID) v = *(const float4*)(W1 + (size_t)(k0 + kk) * HID + n);
        tile[kk][nn4 + 0] = v.x; tile[kk][nn4 + 1] = v.y;
        tile[kk][nn4 + 2] = v.z; tile[kk][nn4 + 3] = v.w;
    }
    __syncthreads();
    #pragma unroll
    for (int p2 = 0; p2 < 2; ++p2) {
        int u = t + p2 * 256;               // 0..511
        int rl = u >> 3, cphys = u & 7;
        int r = n0 + rl;
        if (r < NP) {
            int ck = cphys ^ (r & 7);
            f16x8 o;
            #pragma unroll
            for (int h = 0; h < 8; ++h) o[h] = (f16)tile[ck * 8 + h][rl];
            *(f16x8*)(Bsw + ((size_t)kt * TUB + r * 8 + cphys) * 8) = o;
        }
    }
}

// ============ 2. GEMM: CP[ky][row][c] (f16) = A[:, kchunk] @ B ============
// B fill->LDS double-buffer, A reg->LDS. m201-style sync: builtin s_barrier (no memory
// clobber) + counted vmcnt asm + sched_barrier pins -> prefetches survive the barrier.
__global__ __launch_bounds__(512, 4) void k_gemm(const float* __restrict__ A,
                                                 const f16* __restrict__ Bsw,
                                                 f16* __restrict__ CP) {
    __shared__ __align__(16) f16 Ah[BM * BK];            // 16 KB
    __shared__ __align__(16) f16 Bf0[BFSZ], Bf1[BFSZ];   // 2 x 32 KB  (total 80 KB -> 2 blk/CU)

    const int t = threadIdx.x;
    const int lane = t & 63, wv = t >> 6;
    const int wm = wv >> 1, wn = wv & 1;
    const int l15 = lane & 15, g = lane >> 4;
    const int bid = blockIdx.x;
    const int ky = bid & 7;            // k-chunk; round-robin -> per-XCD B slice in L2
    const int bx = bid >> 3;
    const int m0 = bx * BM;
    const int kt0 = ky * NT;
    const size_t kc0 = (size_t)ky * KCH;

    // A staging: thread owns row ar, 16 halves = units ac, ac+1 (swizzled)
    const int ar = t >> 2;
    const int ac = (t & 3) * 2;
    const int swzA = ar & 7;
    f16* aw0 = &Ah[(ar * 8 + ((ac + 0) ^ swzA)) * 8];
    f16* aw1 = &Ah[(ar * 8 + ((ac + 1) ^ swzA)) * 8];
    const float* ap = A + (size_t)(m0 + ar) * KD + kc0 + (size_t)(t & 3) * 16;
    const f16* bsrc = Bsw + ((size_t)kt0 * TUB + (size_t)t) * 8;

    f32x4 acc[2][7];
    #pragma unroll
    for (int m = 0; m < 2; ++m)
        #pragma unroll
        for (int n = 0; n < 7; ++n) acc[m][n] = (f32x4){0.f, 0.f, 0.f, 0.f};

    float4 v0, v1, v2, v3;
#define LOADA(i) { const float* p_ = ap + (size_t)(i) * BK;            \
        v0 = *(const float4*)(p_);      v1 = *(const float4*)(p_ + 4);  \
        v2 = *(const float4*)(p_ + 8);  v3 = *(const float4*)(p_ + 12); }
#define CONV_STORE() { f16x8 h0_, h1_;                                        \
        h0_[0]=(f16)v0.x; h0_[1]=(f16)v0.y; h0_[2]=(f16)v0.z; h0_[3]=(f16)v0.w; \
        h0_[4]=(f16)v1.x; h0_[5]=(f16)v1.y; h0_[6]=(f16)v1.z; h0_[7]=(f16)v1.w; \
        h1_[0]=(f16)v2.x; h1_[1]=(f16)v2.y; h1_[2]=(f16)v2.z; h1_[3]=(f16)v2.w; \
        h1_[4]=(f16)v3.x; h1_[5]=(f16)v3.y; h1_[6]=(f16)v3.z; h1_[7]=(f16)v3.w; \
        *(f16x8*)aw0 = h0_; *(f16x8*)aw1 = h1_; }
#define FILLB(i, BF) { const f16* bs_ = bsrc + (size_t)(i) * (TUB * 8);  \
        fill16(bs_,             &BF[(size_t)t * 8]);                     \
        fill16(bs_ +  512 * 8,  &BF[((size_t)t +  512) * 8]);            \
        fill16(bs_ + 1024 * 8,  &BF[((size_t)t + 1024) * 8]);            \
        fill16(bs_ + 1536 * 8,  &BF[((size_t)t + 1536) * 8]); }
#define MFMA_PH(BF) {                                                         \
        _Pragma("unroll")                                                     \
        for (int kk = 0; kk < 2; ++kk) {                                      \
            const int cu = kk * 4 + g;                                        \
            f16x8 a0_, a1_;                                                   \
            { int r = wm * 32 + l15;      a0_ = *(const f16x8*)&Ah[(r * 8 + (cu ^ (r & 7))) * 8]; } \
            { int r = wm * 32 + 16 + l15; a1_ = *(const f16x8*)&Ah[(r * 8 + (cu ^ (r & 7))) * 8]; } \
            _Pragma("unroll")                                                 \
            for (int n = 0; n < 7; ++n) {                                     \
                int cr = wn * 112 + n * 16 + l15;                             \
                f16x8 b_ = *(const f16x8*)&BF[(cr * 8 + (cu ^ (cr & 7))) * 8]; \
                acc[0][n] = __builtin_amdgcn_mfma_f32_16x16x32_f16(a0_, b_, acc[0][n], 0, 0, 0); \
                acc[1][n] = __builtin_amdgcn_mfma_f32_16x16x32_f16(a1_, b_, acc[1][n], 0, 0, 0); } } }

    // body: FIFO at wait = fills(i+1)[4] + loadsA(i+1)[8] = 12 -> vmcnt(12) keeps them in
    // flight; fills(i) are older and get drained by the CONV's compiler-counted vmcnt(4).
#define BODY(i, BFN, BFC, LAST) {                                             \
        if (!(LAST)) FILLB((i) + 1, BFN);                                     \
        CONV_STORE();                                                         \
        if (!(LAST)) LOADA((i) + 1);                                          \
        __builtin_amdgcn_sched_barrier(0);                                    \
        if (LAST) { asm volatile("s_waitcnt vmcnt(0) lgkmcnt(0)"); }          \
        else      { asm volatile("s_waitcnt vmcnt(12) lgkmcnt(0)"); }         \
        __builtin_amdgcn_sched_barrier(0);                                    \
        __builtin_amdgcn_s_barrier();                                         \
        __builtin_amdgcn_sched_barrier(0);                                    \
        __builtin_amdgcn_s_setprio(1);                                        \
        MFMA_PH(BFC);                                                         \
        __builtin_amdgcn_s_setprio(0);                                        \
        __builtin_amdgcn_sched_barrier(0);                                    \
        __builtin_amdgcn_s_barrier();                                         \
    }

    FILLB(0, Bf0);
    LOADA(0);
    #pragma unroll 1
    for (int ip = 0; ip < NT / 2 - 1; ++ip) {
        const int i = 2 * ip;
        BODY(i,     Bf1, Bf0, false);
        BODY(i + 1, Bf0, Bf1, false);
    }
    BODY(NT - 2, Bf1, Bf0, false);
    BODY(NT - 1, Bf0, Bf1, true);
#undef LOADA
#undef CONV_STORE
#undef FILLB
#undef MFMA_PH
#undef BODY

    f16* o = CP + (size_t)ky * ((size_t)NN * NP);
    #pragma unroll
    for (int m = 0; m < 2; ++m) {
        #pragma unroll
        for (int n = 0; n < 7; ++n) {
            int rb = m0 + wm * 32 + m * 16 + g * 4;
            int c = wn * 112 + n * 16 + l15;
            #pragma unroll
            for (int r = 0; r < 4; ++r)
                o[(size_t)(rb + r) * NP + c] = (f16)acc[m][n][r];
        }
    }
}

// ============ 3. combine partials -> BS1 (swizzled-tile, transposed) ============
__global__ __launch_bounds__(256) void k_combine_b(const f16* __restrict__ CP,
                                                   f16* __restrict__ Bsw) {
    __shared__ float tile[64][65];
    const size_t SZ = (size_t)NN * NP;
    const int kt = blockIdx.x;          // S1-row block kt*64 -> tile kt
    const int n0 = blockIdx.y * 64;
    const int k0 = kt * 64;
    const int t = threadIdx.x;
    #pragma unroll
    for (int q = 0; q < 4; ++q) {
        int idx4 = t + q * 256;
        int kk = idx4 >> 4, nn4 = (idx4 & 15) * 4;
        int n = n0 + nn4;
        float s0 = 0.f, s1 = 0.f, s2 = 0.f, s3 = 0.f;
        if (n < NP) {
            #pragma unroll
            for (int p = 0; p < KS; ++p) {
                f16x4 v = *(const f16x4*)(CP + (size_t)p * SZ + (size_t)(k0 + kk) * NP + n);
                s0 += (float)v[0]; s1 += (float)v[1]; s2 += (float)v[2]; s3 += (float)v[3];
            }
        }
        tile[kk][nn4 + 0] = s0; tile[kk][nn4 + 1] = s1;
        tile[kk][nn4 + 2] = s2; tile[kk][nn4 + 3] = s3;
    }
    __syncthreads();
    #pragma unroll
    for (int p2 = 0; p2 < 2; ++p2) {
        int u = t + p2 * 256;
        int rl = u >> 3, cphys = u & 7;
        int r = n0 + rl;
        if (r < NP) {
            int ck = cphys ^ (r & 7);
            f16x8 o;
            #pragma unroll
            for (int h = 0; h < 8; ++h) o[h] = (f16)tile[ck * 8 + h][rl];
            *(f16x8*)(Bsw + ((size_t)kt * TUB + r * 8 + cphys) * 8) = o;
        }
    }
}

// ============ 4. fused tail: H = relu(sum CP + b1); S2T = (H @ W2)^T ============
__global__ __launch_bounds__(256) void k_tail(const f16* __restrict__ CP,
                                              const float* __restrict__ b1,
                                              const float* __restrict__ W2,
                                              float* __restrict__ S2T) {
    const int tx = threadIdx.x;         // 0..31
    const int ty = threadIdx.y;         // 0..7
    const int row = blockIdx.x * 8 + ty;
    float s[OUTC] = {0.f, 0.f, 0.f, 0.f, 0.f};
    if (tx < 28) {
        const size_t SZ = (size_t)NN * NP;
        const size_t off = (size_t)row * NP + tx * 8;
        float h[8] = {0.f,0.f,0.f,0.f,0.f,0.f,0.f,0.f};
        #pragma unroll
        for (int p = 0; p < KS; ++p) {
            f16x8 v = *(const f16x8*)(CP + (size_t)p * SZ + off);
            #pragma unroll
            for (int j = 0; j < 8; ++j) h[j] += (float)v[j];
        }
        #pragma unroll
        for (int j = 0; j < 8; ++j) {
            int c = tx * 8 + j;
            if (c < HID) {
                float hv = fmaxf(h[j] + b1[c], 0.f);
                #pragma unroll
                for (int q = 0; q < OUTC; ++q) s[q] += hv * W2[c * OUTC + q];
            }
        }
    }
    #pragma unroll
    for (int q = 0; q < OUTC; ++q)
        #pragma unroll
        for (int off2 = 16; off2; off2 >>= 1) s[q] += __shfl_down(s[q], off2, 32);
    if (tx == 0) {
        #pragma unroll
        for (int q = 0; q < OUTC; ++q) S2T[(size_t)q * NN + row] = s[q];
    }
}

// ============ 5. softmax(adj @ S2 + b2) -> out (adj fp32) ============
__global__ __launch_bounds__(256) void k_final(const float* __restrict__ adj,
                                               const float* __restrict__ S2T,
                                               const float* __restrict__ b2,
                                               float* __restrict__ out) {
    __shared__ float red[4][8][OUTC];
    const int t = threadIdx.x, wave = t >> 6, lane = t & 63;
    const int row0 = blockIdx.x * 8;
    float acc[8][OUTC];
    #pragma unroll
    for (int r = 0; r < 8; ++r)
        #pragma unroll
        for (int c = 0; c < OUTC; ++c) acc[r][c] = 0.f;

    for (int jj = 0; jj < 8; ++jj) {
        int kb = (t + jj * 256) * 4;
        float4 s2[OUTC];
        #pragma unroll
        for (int c = 0; c < OUTC; ++c) s2[c] = *(const float4*)(S2T + (size_t)c * NN + kb);
        #pragma unroll
        for (int r = 0; r < 8; ++r) {
            float4 a = *(const float4*)(adj + (size_t)(row0 + r) * KD + kb);
            #pragma unroll
            for (int c = 0; c < OUTC; ++c)
                acc[r][c] += a.x * s2[c].x + a.y * s2[c].y + a.z * s2[c].z + a.w * s2[c].w;
        }
    }
    #pragma unroll
    for (int r = 0; r < 8; ++r)
        #pragma unroll
        for (int c = 0; c < OUTC; ++c) {
            float v = acc[r][c];
            #pragma unroll
            for (int off = 32; off; off >>= 1) v += __shfl_down(v, off, 64);
            if (lane == 0) red[wave][r][c] = v;
        }
    __syncthreads();
    if (t < 8) {
        int r = t;
        float lg[OUTC];
        #pragma unroll
        for (int c = 0; c < OUTC; ++c)
            lg[c] = red[0][r][c] + red[1][r][c] + red[2][r][c] + red[3][r][c] + b2[c];
        float mx = lg[0];
        #pragma unroll
        for (int c = 1; c < OUTC; ++c) mx = fmaxf(mx, lg[c]);
        float e[OUTC], ssum = 0.f;
        #pragma unroll
        for (int c = 0; c < OUTC; ++c) { e[c] = expf(lg[c] - mx); ssum += e[c]; }
        float inv = 1.0f / ssum;
        #pragma unroll
        for (int c = 0; c < OUTC; ++c) out[(size_t)(row0 + r) * OUTC + c] = e[c] * inv;
    }
}

// ===================== launcher =====================
extern "C" void kernel_launch(void* const* d_in, const int* in_sizes, int n_in,
                              void* d_out, int out_size, void* d_ws, size_t ws_size,
                              hipStream_t stream) {
    const float* x   = (const float*)d_in[0];
    const float* adj = (const float*)d_in[1];
    const float* W1  = (const float*)d_in[2];
    const float* b1  = (const float*)d_in[3];
    const float* W2  = (const float*)d_in[4];
    const float* b2  = (const float*)d_in[5];
    float* out = (float*)d_out;

    char* ws = (char*)d_ws;
    const size_t BSZ = (size_t)128 * TUB * 16;                 // 4 MB per B' array (128 tiles)
    f16*   BW1 = (f16*)(ws);
    f16*   BS1 = (f16*)(ws + BSZ);
    float* S2T = (float*)(ws + 2 * BSZ);
    f16*   CP  = (f16*)(ws + 2 * BSZ + 256 * 1024);            // 8 * NN*NP f16 = 29.4 MB

    // 1. W1 -> swizzled-tile fp16 (B' format)
    k_prep_w1<<<dim3(128, 4), 256, 0, stream>>>(W1, BW1);
    // 2. S1 = x @ W1 (K-split fp16 partials)
    k_gemm<<<dim3(512), 512, 0, stream>>>(x, BW1, CP);
    // 3. reduce partials -> BS1 (B' format, transposed)
    k_combine_b<<<dim3(128, 4), 256, 0, stream>>>(CP, BS1);
    // 4. adj @ S1 (K-split fp16 partials)
    k_gemm<<<dim3(512), 512, 0, stream>>>(adj, BS1, CP);
    // 5. fused: H = relu(sum + b1); S2^T = (H @ W2)^T
    k_tail<<<dim3(NN / 8), dim3(32, 8), 0, stream>>>(CP, b1, W2, S2T);
    // 6. softmax(adj @ S2 + b2)
    k_final<<<dim3(NN / 8), 256, 0, stream>>>(adj, S2T, b2, out);
}

// Round 11
// 247.471 us; speedup vs baseline: 1.7056x; 1.1521x over previous
//
#include <hip/hip_runtime.h>
#include <hip/hip_fp16.h>
#include <math.h>

// Problem dims
#define NN   8192
#define KD   8192
#define HID  200
#define NP   224    // HID padded to 14*16
#define OUTC 5

// GEMM tiling
#define BM   128
#define BK   32
#define KS   8
#define KCH  (KD / KS)     // 1024
#define NT   (KCH / BK)    // 32 K-steps per block
#define TUB  1024          // B tile 16B-units (224 rows x 4, padded to 1024; pad never read)
// B swizzle: logical (r, c∈[0,4)) -> phys unit (r*4 + (c ^ (r&3))) ^ (r&4)  [bijective on r<224]
// A tile: 128 rows x 32 k fp32 = 1024 16B-units; LDS unit u holds row u>>3, c4 = (u&7)^(row&7)
//   (pre-swizzled global source); reader phys = r*8 + (c4 ^ (r&7)) -> conflict-free b128.

typedef _Float16 f16;
typedef __attribute__((ext_vector_type(4))) _Float16 f16x4;
typedef __attribute__((ext_vector_type(8))) _Float16 f16x8;
typedef __attribute__((ext_vector_type(4))) float f32x4;

__device__ __forceinline__ int swzb(int r, int c) {
    return (r * 4 + (c ^ (r & 3))) ^ (r & 4);
}

__device__ __forceinline__ void fill16(const void* g, void* l) {
    __builtin_amdgcn_global_load_lds(
        (const __attribute__((address_space(1))) void*)g,
        (__attribute__((address_space(3))) void*)l, 16, 0, 0);
}

// ============ 1. W1 [8192][200] fp32 -> BW1 swizzled-tile fp16 (2 tiles of 32k per block) ======
__global__ __launch_bounds__(256) void k_prep_w1(const float* __restrict__ W1,
                                                 f16* __restrict__ Bsw) {
    __shared__ float tile[64][65];
    const int bx = blockIdx.x;          // k0 = bx*64 -> tiles 2bx, 2bx+1 (32 k each)
    const int n0 = blockIdx.y * 64;
    const int k0 = bx * 64;
    const int t = threadIdx.x;
    #pragma unroll
    for (int q = 0; q < 4; ++q) {
        int idx4 = t + q * 256;
        int kk = idx4 >> 4, nn4 = (idx4 & 15) * 4;
        int n = n0 + nn4;
        float4 v = {0.f, 0.f, 0.f, 0.f};
        if (n + 4 <= HID) v = *(const float4*)(W1 + (size_t)(k0 + kk) * HID + n);
        tile[kk][nn4 + 0] = v.x; tile[kk][nn4 + 1] = v.y;
        tile[kk][nn4 + 2] = v.z; tile[kk][nn4 + 3] = v.w;
    }
    __syncthreads();
    #pragma unroll
    for (int p2 = 0; p2 < 2; ++p2) {
        int u = t + p2 * 256;               // 0..511
        int rl = u >> 3, cc = u & 7;
        int ktl = cc >> 2, c = cc & 3;
        int r = n0 + rl;
        if (r < NP) {
            f16x8 o;
            #pragma unroll
            for (int h = 0; h < 8; ++h) o[h] = (f16)tile[ktl * 32 + c * 8 + h][rl];
            *(f16x8*)(Bsw + ((size_t)(bx * 2 + ktl) * TUB + swzb(r, c)) * 8) = o;
        }
    }
}

// ============ 2. GEMM: CP[ky][row][c] (f16) = A[:, kchunk] @ B ============
// A and B BOTH via global_load_lds (A as raw fp32, cvt at fragment read). No register
// staging -> no compiler vmcnt coupling. One counted vmcnt(4) + 2 raw barriers per step.
__global__ __launch_bounds__(512, 4) void k_gemm(const float* __restrict__ A,
                                                 const f16* __restrict__ Bsw,
                                                 f16* __restrict__ CP) {
    __shared__ __align__(16) float Af0[1024 * 4], Af1[1024 * 4];   // 2 x 16 KB (fp32 A tile)
    __shared__ __align__(16) f16   Bf0[TUB * 8],  Bf1[TUB * 8];    // 2 x 16 KB

    const int t = threadIdx.x;
    const int lane = t & 63, wv = t >> 6;
    const int wm = wv >> 1, wn = wv & 1;
    const int l15 = lane & 15, g = lane >> 4;
    const int bid = blockIdx.x;
    const int ky = bid & 7;            // k-chunk; round-robin -> per-XCD B slice in L2
    const int bx = bid >> 3;
    const int m0 = bx * BM;
    const int kt0 = ky * NT;
    const size_t kc0 = (size_t)ky * KCH;

    // A fill source (pre-swizzled): LDS unit u <- row u>>3, c4 = (u&7)^(row&7)
    const int u0 = t, u1 = t + 512;
    const int ar0 = u0 >> 3, ac0 = (u0 & 7) ^ (ar0 & 7);
    const int ar1 = u1 >> 3, ac1 = (u1 & 7) ^ (ar1 & 7);
    const float* asrc0 = A + (size_t)(m0 + ar0) * KD + kc0 + (size_t)ac0 * 4;
    const float* asrc1 = A + (size_t)(m0 + ar1) * KD + kc0 + (size_t)ac1 * 4;
    const f16* bsrc = Bsw + ((size_t)kt0 * TUB + (size_t)t) * 8;

    f32x4 acc[2][7];
    #pragma unroll
    for (int m = 0; m < 2; ++m)
        #pragma unroll
        for (int n = 0; n < 7; ++n) acc[m][n] = (f32x4){0.f, 0.f, 0.f, 0.f};

#define FILLS(i, AF, BF) {                                              \
        fill16(asrc0 + (size_t)(i) * BK, &AF[(size_t)u0 * 4]);          \
        fill16(asrc1 + (size_t)(i) * BK, &AF[(size_t)u1 * 4]);          \
        const f16* bs_ = bsrc + (size_t)(i) * (TUB * 8);                \
        fill16(bs_,           &BF[(size_t)u0 * 8]);                     \
        fill16(bs_ + 512 * 8, &BF[(size_t)u1 * 8]); }

#define MFMA_PH(AF, BF) {                                               \
        f16x8 am_[2];                                                   \
        _Pragma("unroll")                                               \
        for (int m = 0; m < 2; ++m) {                                   \
            int r_ = wm * 32 + m * 16 + l15;                            \
            int p0_ = r_ * 8 + ((2 * g)     ^ (r_ & 7));                \
            int p1_ = r_ * 8 + ((2 * g + 1) ^ (r_ & 7));                \
            float4 fa_ = *(const float4*)&AF[(size_t)p0_ * 4];          \
            float4 fb_ = *(const float4*)&AF[(size_t)p1_ * 4];          \
            f16x8 a_;                                                   \
            a_[0]=(f16)fa_.x; a_[1]=(f16)fa_.y; a_[2]=(f16)fa_.z; a_[3]=(f16)fa_.w; \
            a_[4]=(f16)fb_.x; a_[5]=(f16)fb_.y; a_[6]=(f16)fb_.z; a_[7]=(f16)fb_.w; \
            am_[m] = a_;                                                \
        }                                                               \
        _Pragma("unroll")                                               \
        for (int n = 0; n < 7; ++n) {                                   \
            int cr_ = wn * 112 + n * 16 + l15;                          \
            f16x8 b_ = *(const f16x8*)&BF[(size_t)swzb(cr_, g) * 8];    \
            acc[0][n] = __builtin_amdgcn_mfma_f32_16x16x32_f16(am_[0], b_, acc[0][n], 0, 0, 0); \
            acc[1][n] = __builtin_amdgcn_mfma_f32_16x16x32_f16(am_[1], b_, acc[1][n], 0, 0, 0); } }

    // body: fills(i+1) issued, then wait vmcnt(4) = fills(i) landed, fills(i+1) stay in flight
#define BODY(i, AFN, BFN, AFC, BFC, DOFILL, LAST) {                     \
        if (DOFILL) FILLS((i) + 1, AFN, BFN);                           \
        __builtin_amdgcn_sched_barrier(0);                              \
        if (DOFILL) { asm volatile("s_waitcnt vmcnt(4)"); }             \
        else        { asm volatile("s_waitcnt vmcnt(0)"); }             \
        __builtin_amdgcn_sched_barrier(0);                              \
        __builtin_amdgcn_s_barrier();                                   \
        __builtin_amdgcn_sched_barrier(0);                              \
        __builtin_amdgcn_s_setprio(1);                                  \
        MFMA_PH(AFC, BFC);                                              \
        __builtin_amdgcn_s_setprio(0);                                  \
        __builtin_amdgcn_sched_barrier(0);                              \
        if (!(LAST)) {                                                  \
            asm volatile("s_waitcnt lgkmcnt(0)");                       \
            __builtin_amdgcn_s_barrier();                               \
            __builtin_amdgcn_sched_barrier(0);                          \
        } }

    FILLS(0, Af0, Bf0);
    #pragma unroll 1
    for (int ip = 0; ip < NT / 2; ++ip) {
        const int i = 2 * ip;
        BODY(i,     Af1, Bf1, Af0, Bf0, true,            false);
        BODY(i + 1, Af0, Bf0, Af1, Bf1, (i + 2 < NT),    (i + 1 == NT - 1));
    }
#undef FILLS
#undef MFMA_PH
#undef BODY

    f16* o = CP + (size_t)ky * ((size_t)NN * NP);
    #pragma unroll
    for (int m = 0; m < 2; ++m) {
        #pragma unroll
        for (int n = 0; n < 7; ++n) {
            int rb = m0 + wm * 32 + m * 16 + g * 4;
            int c = wn * 112 + n * 16 + l15;
            #pragma unroll
            for (int r = 0; r < 4; ++r)
                o[(size_t)(rb + r) * NP + c] = (f16)acc[m][n][r];
        }
    }
}

// ============ 3. combine partials -> BS1 (swizzled-tile, transposed) ============
__global__ __launch_bounds__(256) void k_combine_b(const f16* __restrict__ CP,
                                                   f16* __restrict__ Bsw) {
    __shared__ float tile[64][65];
    const size_t SZ = (size_t)NN * NP;
    const int bx = blockIdx.x;          // S1-row block bx*64 -> tiles 2bx, 2bx+1
    const int n0 = blockIdx.y * 64;
    const int k0 = bx * 64;
    const int t = threadIdx.x;
    #pragma unroll
    for (int q = 0; q < 4; ++q) {
        int idx4 = t + q * 256;
        int kk = idx4 >> 4, nn4 = (idx4 & 15) * 4;
        int n = n0 + nn4;
        float s0 = 0.f, s1 = 0.f, s2 = 0.f, s3 = 0.f;
        if (n < NP) {
            #pragma unroll
            for (int p = 0; p < KS; ++p) {
                f16x4 v = *(const f16x4*)(CP + (size_t)p * SZ + (size_t)(k0 + kk) * NP + n);
                s0 += (float)v[0]; s1 += (float)v[1]; s2 += (float)v[2]; s3 += (float)v[3];
            }
        }
        tile[kk][nn4 + 0] = s0; tile[kk][nn4 + 1] = s1;
        tile[kk][nn4 + 2] = s2; tile[kk][nn4 + 3] = s3;
    }
    __syncthreads();
    #pragma unroll
    for (int p2 = 0; p2 < 2; ++p2) {
        int u = t + p2 * 256;
        int rl = u >> 3, cc = u & 7;
        int ktl = cc >> 2, c = cc & 3;
        int r = n0 + rl;
        if (r < NP) {
            f16x8 o;
            #pragma unroll
            for (int h = 0; h < 8; ++h) o[h] = (f16)tile[ktl * 32 + c * 8 + h][rl];
            *(f16x8*)(Bsw + ((size_t)(bx * 2 + ktl) * TUB + swzb(r, c)) * 8) = o;
        }
    }
}

// ============ 4. fused tail: H = relu(sum CP + b1); S2T = (H @ W2)^T ============
__global__ __launch_bounds__(256) void k_tail(const f16* __restrict__ CP,
                                              const float* __restrict__ b1,
                                              const float* __restrict__ W2,
                                              float* __restrict__ S2T) {
    const int tx = threadIdx.x;         // 0..31
    const int ty = threadIdx.y;         // 0..7
    const int row = blockIdx.x * 8 + ty;
    float s[OUTC] = {0.f, 0.f, 0.f, 0.f, 0.f};
    if (tx < 28) {
        const size_t SZ = (size_t)NN * NP;
        const size_t off = (size_t)row * NP + tx * 8;
        float h[8] = {0.f,0.f,0.f,0.f,0.f,0.f,0.f,0.f};
        #pragma unroll
        for (int p = 0; p < KS; ++p) {
            f16x8 v = *(const f16x8*)(CP + (size_t)p * SZ + off);
            #pragma unroll
            for (int j = 0; j < 8; ++j) h[j] += (float)v[j];
        }
        #pragma unroll
        for (int j = 0; j < 8; ++j) {
            int c = tx * 8 + j;
            if (c < HID) {
                float hv = fmaxf(h[j] + b1[c], 0.f);
                #pragma unroll
                for (int q = 0; q < OUTC; ++q) s[q] += hv * W2[c * OUTC + q];
            }
        }
    }
    #pragma unroll
    for (int q = 0; q < OUTC; ++q)
        #pragma unroll
        for (int off2 = 16; off2; off2 >>= 1) s[q] += __shfl_down(s[q], off2, 32);
    if (tx == 0) {
        #pragma unroll
        for (int q = 0; q < OUTC; ++q) S2T[(size_t)q * NN + row] = s[q];
    }
}

// ============ 5. softmax(adj @ S2 + b2) -> out (adj fp32) ============
__global__ __launch_bounds__(256) void k_final(const float* __restrict__ adj,
                                               const float* __restrict__ S2T,
                                               const float* __restrict__ b2,
                                               float* __restrict__ out) {
    __shared__ float red[4][8][OUTC];
    const int t = threadIdx.x, wave = t >> 6, lane = t & 63;
    const int row0 = blockIdx.x * 8;
    float acc[8][OUTC];
    #pragma unroll
    for (int r = 0; r < 8; ++r)
        #pragma unroll
        for (int c = 0; c < OUTC; ++c) acc[r][c] = 0.f;

    for (int jj = 0; jj < 8; ++jj) {
        int kb = (t + jj * 256) * 4;
        float4 s2[OUTC];
        #pragma unroll
        for (int c = 0; c < OUTC; ++c) s2[c] = *(const float4*)(S2T + (size_t)c * NN + kb);
        #pragma unroll
        for (int r = 0; r < 8; ++r) {
            float4 a = *(const float4*)(adj + (size_t)(row0 + r) * KD + kb);
            #pragma unroll
            for (int c = 0; c < OUTC; ++c)
                acc[r][c] += a.x * s2[c].x + a.y * s2[c].y + a.z * s2[c].z + a.w * s2[c].w;
        }
    }
    #pragma unroll
    for (int r = 0; r < 8; ++r)
        #pragma unroll
        for (int c = 0; c < OUTC; ++c) {
            float v = acc[r][c];
            #pragma unroll
            for (int off = 32; off; off >>= 1) v += __shfl_down(v, off, 64);
            if (lane == 0) red[wave][r][c] = v;
        }
    __syncthreads();
    if (t < 8) {
        int r = t;
        float lg[OUTC];
        #pragma unroll
        for (int c = 0; c < OUTC; ++c)
            lg[c] = red[0][r][c] + red[1][r][c] + red[2][r][c] + red[3][r][c] + b2[c];
        float mx = lg[0];
        #pragma unroll
        for (int c = 1; c < OUTC; ++c) mx = fmaxf(mx, lg[c]);
        float e[OUTC], ssum = 0.f;
        #pragma unroll
        for (int c = 0; c < OUTC; ++c) { e[c] = expf(lg[c] - mx); ssum += e[c]; }
        float inv = 1.0f / ssum;
        #pragma unroll
        for (int c = 0; c < OUTC; ++c) out[(size_t)(row0 + r) * OUTC + c] = e[c] * inv;
    }
}

// ===================== launcher =====================
extern "C" void kernel_launch(void* const* d_in, const int* in_sizes, int n_in,
                              void* d_out, int out_size, void* d_ws, size_t ws_size,
                              hipStream_t stream) {
    const float* x   = (const float*)d_in[0];
    const float* adj = (const float*)d_in[1];
    const float* W1  = (const float*)d_in[2];
    const float* b1  = (const float*)d_in[3];
    const float* W2  = (const float*)d_in[4];
    const float* b2  = (const float*)d_in[5];
    float* out = (float*)d_out;

    char* ws = (char*)d_ws;
    const size_t BSZ = (size_t)256 * TUB * 16;                 // 4 MB per B' array (256 tiles)
    f16*   BW1 = (f16*)(ws);
    f16*   BS1 = (f16*)(ws + BSZ);
    float* S2T = (float*)(ws + 2 * BSZ);
    f16*   CP  = (f16*)(ws + 2 * BSZ + 256 * 1024);            // 8 * NN*NP f16 = 29.4 MB

    // 1. W1 -> swizzled-tile fp16 (B' format)
    k_prep_w1<<<dim3(128, 4), 256, 0, stream>>>(W1, BW1);
    // 2. S1 = x @ W1 (K-split fp16 partials)
    k_gemm<<<dim3(512), 512, 0, stream>>>(x, BW1, CP);
    // 3. reduce partials -> BS1 (B' format, transposed)
    k_combine_b<<<dim3(128, 4), 256, 0, stream>>>(CP, BS1);
    // 4. adj @ S1 (K-split fp16 partials)
    k_gemm<<<dim3(512), 512, 0, stream>>>(adj, BS1, CP);
    // 5. fused: H = relu(sum + b1); S2^T = (H @ W2)^T
    k_tail<<<dim3(NN / 8), dim3(32, 8), 0, stream>>>(CP, b1, W2, S2T);
    // 6. softmax(adj @ S2 + b2)
    k_final<<<dim3(NN / 8), 256, 0, stream>>>(adj, S2T, b2, out);
}